// Round 2
// baseline (82.631 us; speedup 1.0000x reference)
//
#include <hip/hip_runtime.h>
#include <hip/hip_bf16.h>
#include <math.h>

// Problem constants
constexpr int N_    = 2;
constexpr int C_TOT = 256;
constexpr int H_    = 128;
constexpr int W_    = 128;
constexpr int OUTS  = 7;
constexpr int NBIN  = OUTS * OUTS;          // 49
constexpr int NSAMP = NBIN * 4;             // 196 sample points per roi
constexpr int PCH   = C_TOT * NBIN;         // 12544 outputs per roi
constexpr float SCALE = 0.125f;
constexpr int CHUNK = 25;                   // bins per output chunk (25 + 24)

// ---------------------------------------------------------------------------
// NCHW -> NHWC transpose of features into workspace.
// ---------------------------------------------------------------------------
__global__ __launch_bounds__(256) void transpose_nchw_nhwc(
    const float* __restrict__ in, float* __restrict__ out) {
  __shared__ float tile[64][65];
  const int nh = blockIdx.z;
  const int n  = nh >> 7;
  const int h  = nh & 127;
  const int c0 = blockIdx.y * 64;
  const int w0 = blockIdx.x * 64;
  const int tx = threadIdx.x;
  const int ty = threadIdx.y;

  const float* src = in + (((size_t)n * C_TOT + c0) * H_ + h) * W_ + w0;
#pragma unroll
  for (int i = 0; i < 16; ++i) {
    const int c = i * 4 + ty;
    tile[c][tx] = src[(size_t)c * (H_ * W_) + tx];
  }
  __syncthreads();
  float* dst = out + (((size_t)n * H_ + h) * W_ + w0) * C_TOT + c0;
#pragma unroll
  for (int i = 0; i < 16; ++i) {
    const int w = i * 4 + ty;
    dst[(size_t)w * C_TOT + tx] = tile[tx][w];
  }
}

// ---------------------------------------------------------------------------
// v2 main kernel. One block / roi, 256 threads = 4 waves.
//  - lane l owns channels 4l..4l+3 (float4 gathers: a wave covers all 256
//    channels of one corner in a single coalesced 1 KB load)
//  - wave w owns bins w, w+4, ... within the current chunk of <=25 bins
//  - orientation mix with static register indices: lane parity q holds
//    orientations 4q+j; val[o'] = rv*pool[o'] + lv*pool[o'+1] needs only
//    __shfl_xor(acc.x, 1); the per-roi rotation (+ind0 mod 8) is applied as
//    an LDS channel remap during copy-out.
//  - obuf chunked to 25 bins (25.6 KB) -> total LDS ~31.9 KB -> 5 blocks/CU
// ---------------------------------------------------------------------------
template <int NB>
__device__ __forceinline__ void do_chunk(
    const float4* __restrict__ ft, float* __restrict__ obuf,
    const int4* __restrict__ sIdx, const float4* __restrict__ sW,
    float* __restrict__ outk, int base, int w, int l, int t,
    int ind0, float lv, float rv) {
  for (int i = w; i < NB; i += 4) {
    const int bin = base + i;
    float4 acc = make_float4(0.f, 0.f, 0.f, 0.f);
#pragma unroll
    for (int s = 0; s < 4; ++s) {
      const int4   id = sIdx[bin * 4 + s];
      const float4 wt = sW[bin * 4 + s];
      const float4 a = ft[id.x + l];
      const float4 b = ft[id.y + l];
      const float4 c = ft[id.z + l];
      const float4 d = ft[id.w + l];
      acc.x = fmaf(wt.x, a.x, acc.x); acc.y = fmaf(wt.x, a.y, acc.y);
      acc.z = fmaf(wt.x, a.z, acc.z); acc.w = fmaf(wt.x, a.w, acc.w);
      acc.x = fmaf(wt.y, b.x, acc.x); acc.y = fmaf(wt.y, b.y, acc.y);
      acc.z = fmaf(wt.y, b.z, acc.z); acc.w = fmaf(wt.y, b.w, acc.w);
      acc.x = fmaf(wt.z, c.x, acc.x); acc.y = fmaf(wt.z, c.y, acc.y);
      acc.z = fmaf(wt.z, c.z, acc.z); acc.w = fmaf(wt.z, c.w, acc.w);
      acc.x = fmaf(wt.w, d.x, acc.x); acc.y = fmaf(wt.w, d.y, acc.y);
      acc.z = fmaf(wt.w, d.z, acc.z); acc.w = fmaf(wt.w, d.w, acc.w);
    }
    // orientation mix, static indices; pool[o'] for o'=4q+j is acc[j],
    // pool[(4q+3)+1] is partner lane's acc.x
    const float othx = __shfl_xor(acc.x, 1);
    float4 r;
    r.x = rv * acc.x + lv * acc.y;
    r.y = rv * acc.y + lv * acc.z;
    r.z = rv * acc.z + lv * acc.w;
    r.w = rv * acc.w + lv * othx;
    // store at logical (unrotated) channel 4l+j; swizzle (i+l)%25 spreads
    // banks (lane step = 101 floats == 5 mod 32 -> conflict-free)
    const int sw = (i + l) % 25;
    float* p = obuf + (4 * l) * CHUNK + sw;
    p[0]         = r.x;
    p[CHUNK]     = r.y;
    p[2 * CHUNK] = r.z;
    p[3 * CHUNK] = r.w;
  }
  __syncthreads();
  // copy out; apply the orientation rotation as a channel remap
  for (int j = t; j < 256 * NB; j += 256) {
    const int c_out = j / NB;
    const int bb    = j - c_out * NB;
    const int c_lds = (c_out & 0xF8) | ((c_out - ind0) & 7);
    const int s     = (bb + (c_lds >> 2)) % 25;
    outk[c_out * NBIN + base + bb] = obuf[c_lds * CHUNK + s];
  }
  __syncthreads();
}

__global__ __launch_bounds__(256) void os2_rroialign_v2(
    const float4* __restrict__ ft, const float* __restrict__ rois,
    float* __restrict__ out) {
  __shared__ float  obuf[C_TOT * CHUNK];   // 25600 B
  __shared__ int4   sIdx[NSAMP];           // 3136 B
  __shared__ float4 sW[NSAMP];             // 3136 B

  const int k = blockIdx.x;
  const int t = threadIdx.x;

  const float* roi = rois + (size_t)k * 6;
  const float th = roi[5];

  if (t < NSAMP) {
    const int   b  = (int)roi[0];
    const float cx = roi[1] * SCALE;
    const float cy = roi[2] * SCALE;
    const float rw = fmaxf(roi[3] * SCALE, 1.0f);
    const float rh = fmaxf(roi[4] * SCALE, 1.0f);
    const float binw = rw / (float)OUTS;
    const float binh = rh / (float)OUTS;
    const float cs = cosf(th);
    const float sn = sinf(th);

    const int bin = t >> 2;
    const int sub = t & 3;
    const int ph  = bin / 7;
    const int pw  = bin - ph * 7;
    const float fy = (float)ph + ((float)(sub >> 1) + 0.5f) * 0.5f;
    const float fx = (float)pw + ((float)(sub & 1)  + 0.5f) * 0.5f;
    const float yy = -rh * 0.5f + fy * binh;
    const float xx = -rw * 0.5f + fx * binw;
    float x = xx * cs - yy * sn + cx;
    float y = xx * sn + yy * cs + cy;
    const bool valid = (y >= -1.0f) && (y <= (float)H_) &&
                       (x >= -1.0f) && (x <= (float)W_);
    y = fminf(fmaxf(y, 0.0f), (float)(H_ - 1));
    x = fminf(fmaxf(x, 0.0f), (float)(W_ - 1));
    int y0 = (int)floorf(y); if (y0 > H_ - 1) y0 = H_ - 1;
    int x0 = (int)floorf(x); if (x0 > W_ - 1) x0 = W_ - 1;
    const int y1 = min(y0 + 1, H_ - 1);
    const int x1 = min(x0 + 1, W_ - 1);
    const float ly = y - (float)y0, lx = x - (float)x0;
    const float hy = 1.0f - ly,     hx = 1.0f - lx;
    const float m  = valid ? 0.25f : 0.0f;
    sW[t] = make_float4(hy * hx * m, hy * lx * m, ly * hx * m, ly * lx * m);
    const int pb = b * (H_ * W_);
    // offsets in float4 units: pixel * (C_TOT/4)
    sIdx[t] = make_int4((pb + y0 * W_ + x0) * (C_TOT / 4),
                        (pb + y0 * W_ + x1) * (C_TOT / 4),
                        (pb + y1 * W_ + x0) * (C_TOT / 4),
                        (pb + y1 * W_ + x1) * (C_TOT / 4));
  }

  // orientation params (uniform across block)
  const float indf = th * 1.27323954473516268615f;   // * 8 / (2*pi)
  const float i0f  = floorf(indf);
  const float lv   = indf - i0f;
  const float rv   = 1.0f - lv;
  const int ind0 = ((int)i0f) & 7;

  const int w = t >> 6;
  const int l = t & 63;
  float* outk = out + (size_t)k * PCH;

  __syncthreads();

  do_chunk<25>(ft, obuf, sIdx, sW, outk, 0,  w, l, t, ind0, lv, rv);
  do_chunk<24>(ft, obuf, sIdx, sW, outk, 25, w, l, t, ind0, lv, rv);
}

// ---------------------------------------------------------------------------
// Fallback (NCHW, scalar) — used only if workspace is too small.
// ---------------------------------------------------------------------------
__global__ __launch_bounds__(256) void os2_rroialign_nchw(
    const float* __restrict__ ft, const float* __restrict__ rois,
    float* __restrict__ out) {
  __shared__ __align__(16) float outBuf[PCH];
  __shared__ int4   sIdx[NSAMP];
  __shared__ float4 sW[NSAMP];

  const int k = blockIdx.x;
  const int t = threadIdx.x;

  const float* roi = rois + (size_t)k * 6;
  const float th = roi[5];

  if (t < NSAMP) {
    const int   b  = (int)roi[0];
    const float cx = roi[1] * SCALE;
    const float cy = roi[2] * SCALE;
    const float rw = fmaxf(roi[3] * SCALE, 1.0f);
    const float rh = fmaxf(roi[4] * SCALE, 1.0f);
    const float binw = rw / (float)OUTS;
    const float binh = rh / (float)OUTS;
    const float cs = cosf(th);
    const float sn = sinf(th);
    const int bin = t >> 2;
    const int sub = t & 3;
    const int ph  = bin / 7;
    const int pw  = bin - ph * 7;
    const float fy = (float)ph + ((float)(sub >> 1) + 0.5f) * 0.5f;
    const float fx = (float)pw + ((float)(sub & 1)  + 0.5f) * 0.5f;
    const float yy = -rh * 0.5f + fy * binh;
    const float xx = -rw * 0.5f + fx * binw;
    float x = xx * cs - yy * sn + cx;
    float y = xx * sn + yy * cs + cy;
    const bool valid = (y >= -1.0f) && (y <= (float)H_) &&
                       (x >= -1.0f) && (x <= (float)W_);
    y = fminf(fmaxf(y, 0.0f), (float)(H_ - 1));
    x = fminf(fmaxf(x, 0.0f), (float)(W_ - 1));
    int y0 = (int)floorf(y); if (y0 > H_ - 1) y0 = H_ - 1;
    int x0 = (int)floorf(x); if (x0 > W_ - 1) x0 = W_ - 1;
    const int y1 = min(y0 + 1, H_ - 1);
    const int x1 = min(x0 + 1, W_ - 1);
    const float ly = y - (float)y0, lx = x - (float)x0;
    const float hy = 1.0f - ly,     hx = 1.0f - lx;
    const float m  = valid ? 0.25f : 0.0f;
    sW[t] = make_float4(hy * hx * m, hy * lx * m, ly * hx * m, ly * lx * m);
    const int cb = b * C_TOT * H_ * W_;
    sIdx[t] = make_int4(cb + y0 * W_ + x0, cb + y0 * W_ + x1,
                        cb + y1 * W_ + x0, cb + y1 * W_ + x1);
  }

  const float indf = th * 1.27323954473516268615f;
  const float i0f  = floorf(indf);
  const float lv   = indf - i0f;
  const float rv   = 1.0f - lv;
  const int ind0 = ((int)i0f) & 7;
  const int o    = t & 7;
  const int ir   = (o - ind0) & 7;
  const int irp  = (ir + 1) & 7;
  const int grp  = t & 56;
  const int chanOff = t * (H_ * W_);

  __syncthreads();

  for (int bin = 0; bin < NBIN; ++bin) {
    float acc = 0.0f;
#pragma unroll
    for (int s = 0; s < 4; ++s) {
      const int4   id = sIdx[bin * 4 + s];
      const float4 w  = sW[bin * 4 + s];
      acc = fmaf(w.x, ft[id.x + chanOff], acc);
      acc = fmaf(w.y, ft[id.y + chanOff], acc);
      acc = fmaf(w.z, ft[id.z + chanOff], acc);
      acc = fmaf(w.w, ft[id.w + chanOff], acc);
    }
    const float v1 = __shfl(acc, grp | ir,  64);
    const float v2 = __shfl(acc, grp | irp, 64);
    outBuf[t * NBIN + bin] = rv * v1 + lv * v2;
  }

  __syncthreads();
  const float4* ob4 = (const float4*)outBuf;
  float4* o4 = (float4*)(out + (size_t)k * PCH);
#pragma unroll 4
  for (int j = t; j < PCH / 4; j += 256) o4[j] = ob4[j];
}

// ---------------------------------------------------------------------------
extern "C" void kernel_launch(void* const* d_in, const int* in_sizes, int n_in,
                              void* d_out, int out_size, void* d_ws, size_t ws_size,
                              hipStream_t stream) {
  const float* features = (const float*)d_in[0];
  const float* rois     = (const float*)d_in[1];
  float* out            = (float*)d_out;
  const int K = in_sizes[1] / 6;

  const size_t ftBytes = (size_t)N_ * C_TOT * H_ * W_ * sizeof(float);
  if (ws_size >= ftBytes) {
    float* ftT = (float*)d_ws;
    dim3 tb(64, 4);
    dim3 tg(W_ / 64, C_TOT / 64, N_ * H_);
    transpose_nchw_nhwc<<<tg, tb, 0, stream>>>(features, ftT);
    os2_rroialign_v2<<<K, 256, 0, stream>>>((const float4*)ftT, rois, out);
  } else {
    os2_rroialign_nchw<<<K, 256, 0, stream>>>(features, rois, out);
  }
}

// Round 3
// 70.512 us; speedup vs baseline: 1.1719x; 1.1719x over previous
//
#include <hip/hip_runtime.h>
#include <hip/hip_bf16.h>
#include <math.h>

// Problem constants
constexpr int N_    = 2;
constexpr int C_TOT = 256;
constexpr int H_    = 128;
constexpr int W_    = 128;
constexpr int OUTS  = 7;
constexpr int NBIN  = OUTS * OUTS;          // 49
constexpr int NSAMP = NBIN * 4;             // 196 sample points per roi
constexpr int PCH   = C_TOT * NBIN;         // 12544 outputs per roi
constexpr float SCALE = 0.125f;
constexpr int CHALF = C_TOT / 2;            // 128 channels per block

// ---------------------------------------------------------------------------
// NCHW -> NHWC transpose of features into workspace.
// ---------------------------------------------------------------------------
__global__ __launch_bounds__(256) void transpose_nchw_nhwc(
    const float* __restrict__ in, float* __restrict__ out) {
  __shared__ float tile[64][65];
  const int nh = blockIdx.z;
  const int n  = nh >> 7;
  const int h  = nh & 127;
  const int c0 = blockIdx.y * 64;
  const int w0 = blockIdx.x * 64;
  const int tx = threadIdx.x;
  const int ty = threadIdx.y;

  const float* src = in + (((size_t)n * C_TOT + c0) * H_ + h) * W_ + w0;
#pragma unroll
  for (int i = 0; i < 16; ++i) {
    const int c = i * 4 + ty;
    tile[c][tx] = src[(size_t)c * (H_ * W_) + tx];
  }
  __syncthreads();
  float* dst = out + (((size_t)n * H_ + h) * W_ + w0) * C_TOT + c0;
#pragma unroll
  for (int i = 0; i < 16; ++i) {
    const int w = i * 4 + ty;
    dst[(size_t)w * C_TOT + tx] = tile[tx][w];
  }
}

// ---------------------------------------------------------------------------
// v3 main kernel. Grid = (K, 2): one block per (roi, channel-half).
//  - lane l owns channels {2l, 2l+1} of its half (float2 gathers; a wave
//    covers the half's 128 channels of one corner in one 512 B load)
//  - all 49 bins kept in obuf (128 ch x 49 bins = 25 KB) -> the copy-out
//    writes one contiguous 25 KB full-line region per block (no partial-line
//    RMW, unlike the R1 bin-chunked version)
//  - LDS 31.4 KB + __launch_bounds__(256,5) -> 5 blocks/CU (20 waves)
//  - orientation mix with static register indices: acc.x/acc.y are pooled
//    channels c, c+1 of one 8-group; the +1-wrap partner comes from
//    __shfl within the 4-lane subgroup; the per-roi rotation (-ind0 mod 8)
//    is applied as an LDS channel remap during copy-out.
// ---------------------------------------------------------------------------
__global__ __launch_bounds__(256, 5) void os2_rroialign_v3(
    const float2* __restrict__ ft, const float* __restrict__ rois,
    float* __restrict__ out) {
  __shared__ float  obuf[CHALF * NBIN];    // 25088 B
  __shared__ int4   sIdx[NSAMP];           // 3136 B (pixel idx * 128)
  __shared__ float4 sW[NSAMP];             // 3136 B

  const int k    = blockIdx.x;
  const int half = blockIdx.y;
  const int t    = threadIdx.x;

  const float* roi = rois + (size_t)k * 6;
  const float th = roi[5];

  if (t < NSAMP) {
    const int   b  = (int)roi[0];
    const float cx = roi[1] * SCALE;
    const float cy = roi[2] * SCALE;
    const float rw = fmaxf(roi[3] * SCALE, 1.0f);
    const float rh = fmaxf(roi[4] * SCALE, 1.0f);
    const float binw = rw / (float)OUTS;
    const float binh = rh / (float)OUTS;
    const float cs = cosf(th);
    const float sn = sinf(th);

    const int bin = t >> 2;
    const int sub = t & 3;                  // iy*2 + ix
    const int ph  = bin / 7;
    const int pw  = bin - ph * 7;
    const float fy = (float)ph + ((float)(sub >> 1) + 0.5f) * 0.5f;
    const float fx = (float)pw + ((float)(sub & 1)  + 0.5f) * 0.5f;
    const float yy = -rh * 0.5f + fy * binh;
    const float xx = -rw * 0.5f + fx * binw;
    float x = xx * cs - yy * sn + cx;
    float y = xx * sn + yy * cs + cy;
    const bool valid = (y >= -1.0f) && (y <= (float)H_) &&
                       (x >= -1.0f) && (x <= (float)W_);
    y = fminf(fmaxf(y, 0.0f), (float)(H_ - 1));
    x = fminf(fmaxf(x, 0.0f), (float)(W_ - 1));
    int y0 = (int)floorf(y); if (y0 > H_ - 1) y0 = H_ - 1;
    int x0 = (int)floorf(x); if (x0 > W_ - 1) x0 = W_ - 1;
    const int y1 = min(y0 + 1, H_ - 1);
    const int x1 = min(x0 + 1, W_ - 1);
    const float ly = y - (float)y0, lx = x - (float)x0;
    const float hy = 1.0f - ly,     hx = 1.0f - lx;
    const float m  = valid ? 0.25f : 0.0f;
    sW[t] = make_float4(hy * hx * m, hy * lx * m, ly * hx * m, ly * lx * m);
    const int pb = b * (H_ * W_);
    // offsets in float2 units: pixel * (C_TOT/2)
    sIdx[t] = make_int4((pb + y0 * W_ + x0) * (C_TOT / 2),
                        (pb + y0 * W_ + x1) * (C_TOT / 2),
                        (pb + y1 * W_ + x0) * (C_TOT / 2),
                        (pb + y1 * W_ + x1) * (C_TOT / 2));
  }

  // orientation params (uniform across block)
  const float indf = th * 1.27323954473516268615f;   // * 8 / (2*pi)
  const float i0f  = floorf(indf);
  const float lv   = indf - i0f;
  const float rv   = 1.0f - lv;
  const int ind0 = ((int)i0f) & 7;

  const int w = t >> 6;
  const int l = t & 63;
  const int chanOff = half * (CHALF / 2) + l;   // float2 index within pixel
  // shfl partner: lane holding channel c1+1 (wrap within the 8-group == 4-lane subgroup)
  const int src = (l & ~3) | ((l + 1) & 3);

  __syncthreads();

  for (int i = w; i < NBIN; i += 4) {
    float2 acc = make_float2(0.f, 0.f);
#pragma unroll
    for (int s = 0; s < 4; ++s) {
      const int4   id = sIdx[i * 4 + s];
      const float4 wt = sW[i * 4 + s];
      const float2 a = ft[id.x + chanOff];
      const float2 b = ft[id.y + chanOff];
      const float2 c = ft[id.z + chanOff];
      const float2 d = ft[id.w + chanOff];
      acc.x = fmaf(wt.x, a.x, acc.x); acc.y = fmaf(wt.x, a.y, acc.y);
      acc.x = fmaf(wt.y, b.x, acc.x); acc.y = fmaf(wt.y, b.y, acc.y);
      acc.x = fmaf(wt.z, c.x, acc.x); acc.y = fmaf(wt.z, c.y, acc.y);
      acc.x = fmaf(wt.w, d.x, acc.x); acc.y = fmaf(wt.w, d.y, acc.y);
    }
    // orientation mix with static indices:
    //   obuf[c] = rv*pool[c] + lv*pool[next(c)]   (next wraps inside 8-group)
    const float nxt = __shfl(acc.x, src, 64);
    obuf[(2 * l)     * NBIN + i] = rv * acc.x + lv * acc.y;
    obuf[(2 * l + 1) * NBIN + i] = rv * acc.y + lv * nxt;
  }

  __syncthreads();

  // copy-out with rotation remap; one contiguous 25088 B region per block
  float* outh = out + (size_t)k * PCH + (size_t)half * (CHALF * NBIN);
  for (int jj = t * 4; jj < CHALF * NBIN; jj += 1024) {
    float4 v;
#pragma unroll
    for (int e = 0; e < 4; ++e) {
      const int j    = jj + e;
      const int crel = j / NBIN;
      const int bb   = j - crel * NBIN;
      const int clds = (crel & ~7) | ((crel - ind0) & 7);
      (&v.x)[e] = obuf[clds * NBIN + bb];
    }
    *(float4*)(outh + jj) = v;
  }
}

// ---------------------------------------------------------------------------
// Fallback (NCHW, scalar) — used only if workspace is too small.
// ---------------------------------------------------------------------------
__global__ __launch_bounds__(256) void os2_rroialign_nchw(
    const float* __restrict__ ft, const float* __restrict__ rois,
    float* __restrict__ out) {
  __shared__ __align__(16) float outBuf[PCH];
  __shared__ int4   sIdx[NSAMP];
  __shared__ float4 sW[NSAMP];

  const int k = blockIdx.x;
  const int t = threadIdx.x;

  const float* roi = rois + (size_t)k * 6;
  const float th = roi[5];

  if (t < NSAMP) {
    const int   b  = (int)roi[0];
    const float cx = roi[1] * SCALE;
    const float cy = roi[2] * SCALE;
    const float rw = fmaxf(roi[3] * SCALE, 1.0f);
    const float rh = fmaxf(roi[4] * SCALE, 1.0f);
    const float binw = rw / (float)OUTS;
    const float binh = rh / (float)OUTS;
    const float cs = cosf(th);
    const float sn = sinf(th);
    const int bin = t >> 2;
    const int sub = t & 3;
    const int ph  = bin / 7;
    const int pw  = bin - ph * 7;
    const float fy = (float)ph + ((float)(sub >> 1) + 0.5f) * 0.5f;
    const float fx = (float)pw + ((float)(sub & 1)  + 0.5f) * 0.5f;
    const float yy = -rh * 0.5f + fy * binh;
    const float xx = -rw * 0.5f + fx * binw;
    float x = xx * cs - yy * sn + cx;
    float y = xx * sn + yy * cs + cy;
    const bool valid = (y >= -1.0f) && (y <= (float)H_) &&
                       (x >= -1.0f) && (x <= (float)W_);
    y = fminf(fmaxf(y, 0.0f), (float)(H_ - 1));
    x = fminf(fmaxf(x, 0.0f), (float)(W_ - 1));
    int y0 = (int)floorf(y); if (y0 > H_ - 1) y0 = H_ - 1;
    int x0 = (int)floorf(x); if (x0 > W_ - 1) x0 = W_ - 1;
    const int y1 = min(y0 + 1, H_ - 1);
    const int x1 = min(x0 + 1, W_ - 1);
    const float ly = y - (float)y0, lx = x - (float)x0;
    const float hy = 1.0f - ly,     hx = 1.0f - lx;
    const float m  = valid ? 0.25f : 0.0f;
    sW[t] = make_float4(hy * hx * m, hy * lx * m, ly * hx * m, ly * lx * m);
    const int cb = b * C_TOT * H_ * W_;
    sIdx[t] = make_int4(cb + y0 * W_ + x0, cb + y0 * W_ + x1,
                        cb + y1 * W_ + x0, cb + y1 * W_ + x1);
  }

  const float indf = th * 1.27323954473516268615f;
  const float i0f  = floorf(indf);
  const float lv   = indf - i0f;
  const float rv   = 1.0f - lv;
  const int ind0 = ((int)i0f) & 7;
  const int o    = t & 7;
  const int ir   = (o - ind0) & 7;
  const int irp  = (ir + 1) & 7;
  const int grp  = t & 56;
  const int chanOff = t * (H_ * W_);

  __syncthreads();

  for (int bin = 0; bin < NBIN; ++bin) {
    float acc = 0.0f;
#pragma unroll
    for (int s = 0; s < 4; ++s) {
      const int4   id = sIdx[bin * 4 + s];
      const float4 w  = sW[bin * 4 + s];
      acc = fmaf(w.x, ft[id.x + chanOff], acc);
      acc = fmaf(w.y, ft[id.y + chanOff], acc);
      acc = fmaf(w.z, ft[id.z + chanOff], acc);
      acc = fmaf(w.w, ft[id.w + chanOff], acc);
    }
    const float v1 = __shfl(acc, grp | ir,  64);
    const float v2 = __shfl(acc, grp | irp, 64);
    outBuf[t * NBIN + bin] = rv * v1 + lv * v2;
  }

  __syncthreads();
  const float4* ob4 = (const float4*)outBuf;
  float4* o4 = (float4*)(out + (size_t)k * PCH);
#pragma unroll 4
  for (int j = t; j < PCH / 4; j += 256) o4[j] = ob4[j];
}

// ---------------------------------------------------------------------------
extern "C" void kernel_launch(void* const* d_in, const int* in_sizes, int n_in,
                              void* d_out, int out_size, void* d_ws, size_t ws_size,
                              hipStream_t stream) {
  const float* features = (const float*)d_in[0];
  const float* rois     = (const float*)d_in[1];
  float* out            = (float*)d_out;
  const int K = in_sizes[1] / 6;

  const size_t ftBytes = (size_t)N_ * C_TOT * H_ * W_ * sizeof(float);
  if (ws_size >= ftBytes) {
    float* ftT = (float*)d_ws;
    dim3 tb(64, 4);
    dim3 tg(W_ / 64, C_TOT / 64, N_ * H_);
    transpose_nchw_nhwc<<<tg, tb, 0, stream>>>(features, ftT);
    dim3 grid(K, 2);
    os2_rroialign_v3<<<grid, 256, 0, stream>>>((const float2*)ftT, rois, out);
  } else {
    os2_rroialign_nchw<<<K, 256, 0, stream>>>(features, rois, out);
  }
}

// Round 4
// 69.234 us; speedup vs baseline: 1.1935x; 1.0185x over previous
//
#include <hip/hip_runtime.h>
#include <hip/hip_bf16.h>
#include <math.h>

// Problem constants
constexpr int N_    = 2;
constexpr int C_TOT = 256;
constexpr int H_    = 128;
constexpr int W_    = 128;
constexpr int OUTS  = 7;
constexpr int NBIN  = OUTS * OUTS;          // 49
constexpr int NSAMP = NBIN * 4;             // 196 sample points per roi
constexpr int PCH   = C_TOT * NBIN;         // 12544 outputs per roi
constexpr float SCALE = 0.125f;
constexpr int CHALF = C_TOT / 2;            // 128 channels per block
constexpr int OB_LD = CHALF / 2 + 1;        // 65 float2 per obuf row (pad)

// ---------------------------------------------------------------------------
// NCHW -> NHWC transpose of features into workspace.
// ---------------------------------------------------------------------------
__global__ __launch_bounds__(256) void transpose_nchw_nhwc(
    const float* __restrict__ in, float* __restrict__ out) {
  __shared__ float tile[64][65];
  const int nh = blockIdx.z;
  const int n  = nh >> 7;
  const int h  = nh & 127;
  const int c0 = blockIdx.y * 64;
  const int w0 = blockIdx.x * 64;
  const int tx = threadIdx.x;
  const int ty = threadIdx.y;

  const float* src = in + (((size_t)n * C_TOT + c0) * H_ + h) * W_ + w0;
#pragma unroll
  for (int i = 0; i < 16; ++i) {
    const int c = i * 4 + ty;
    tile[c][tx] = src[(size_t)c * (H_ * W_) + tx];
  }
  __syncthreads();
  float* dst = out + (((size_t)n * H_ + h) * W_ + w0) * C_TOT + c0;
#pragma unroll
  for (int i = 0; i < 16; ++i) {
    const int w = i * 4 + ty;
    dst[(size_t)w * C_TOT + tx] = tile[tx][w];
  }
}

// ---------------------------------------------------------------------------
// v4 main kernel. Grid = (K, 2): one block per (roi, channel-half).
// 512 threads = 8 waves; __launch_bounds__(512,8) -> 4 blocks/CU = 32 waves
// (100% occupancy). Lane l owns channels {2l, 2l+1} of its half (float2
// gathers). Wave w handles bins w, w+8, ...
//  - obuf is [bin][chan2] float2 with +1 pad: one ds_write_b64 per bin per
//    lane; lanes l and l+16 share a bank pair (free 2-way) -> kills the
//    R2 4-way conflicts.
//  - 4 partial accumulators (per corner) shorten the FMA dep chain 32 -> 8.
//  - orientation rotation applied as channel remap during copy-out.
// ---------------------------------------------------------------------------
__global__ __launch_bounds__(512, 8) void os2_rroialign_v4(
    const float2* __restrict__ ft, const float* __restrict__ rois,
    float* __restrict__ out) {
  __shared__ float2 obuf[NBIN][OB_LD];     // 49*65*8 = 25480 B
  __shared__ int4   sIdx[NSAMP];           // 3136 B (float2-unit pixel idx)
  __shared__ float4 sW[NSAMP];             // 3136 B

  const int k    = blockIdx.x;
  const int half = blockIdx.y;
  const int t    = threadIdx.x;

  const float* roi = rois + (size_t)k * 6;
  const float th = roi[5];

  if (t < NSAMP) {
    const int   b  = (int)roi[0];
    const float cx = roi[1] * SCALE;
    const float cy = roi[2] * SCALE;
    const float rw = fmaxf(roi[3] * SCALE, 1.0f);
    const float rh = fmaxf(roi[4] * SCALE, 1.0f);
    const float binw = rw / (float)OUTS;
    const float binh = rh / (float)OUTS;
    const float cs = cosf(th);
    const float sn = sinf(th);

    const int bin = t >> 2;
    const int sub = t & 3;                  // iy*2 + ix
    const int ph  = bin / 7;
    const int pw  = bin - ph * 7;
    const float fy = (float)ph + ((float)(sub >> 1) + 0.5f) * 0.5f;
    const float fx = (float)pw + ((float)(sub & 1)  + 0.5f) * 0.5f;
    const float yy = -rh * 0.5f + fy * binh;
    const float xx = -rw * 0.5f + fx * binw;
    float x = xx * cs - yy * sn + cx;
    float y = xx * sn + yy * cs + cy;
    const bool valid = (y >= -1.0f) && (y <= (float)H_) &&
                       (x >= -1.0f) && (x <= (float)W_);
    y = fminf(fmaxf(y, 0.0f), (float)(H_ - 1));
    x = fminf(fmaxf(x, 0.0f), (float)(W_ - 1));
    int y0 = (int)floorf(y); if (y0 > H_ - 1) y0 = H_ - 1;
    int x0 = (int)floorf(x); if (x0 > W_ - 1) x0 = W_ - 1;
    const int y1 = min(y0 + 1, H_ - 1);
    const int x1 = min(x0 + 1, W_ - 1);
    const float ly = y - (float)y0, lx = x - (float)x0;
    const float hy = 1.0f - ly,     hx = 1.0f - lx;
    const float m  = valid ? 0.25f : 0.0f;
    sW[t] = make_float4(hy * hx * m, hy * lx * m, ly * hx * m, ly * lx * m);
    const int pb = b * (H_ * W_);
    // offsets in float2 units: pixel * (C_TOT/2)
    sIdx[t] = make_int4((pb + y0 * W_ + x0) * (C_TOT / 2),
                        (pb + y0 * W_ + x1) * (C_TOT / 2),
                        (pb + y1 * W_ + x0) * (C_TOT / 2),
                        (pb + y1 * W_ + x1) * (C_TOT / 2));
  }

  // orientation params (wave-uniform; force SGPR for the remap math)
  const float indf = th * 1.27323954473516268615f;   // * 8 / (2*pi)
  const float i0f  = floorf(indf);
  const float lv   = indf - i0f;
  const float rv   = 1.0f - lv;
  const int ind0 = __builtin_amdgcn_readfirstlane(((int)i0f) & 7);

  const int w = t >> 6;                    // wave id 0..7
  const int l = t & 63;
  const int chanOff = half * (CHALF / 2) + l;   // float2 index within pixel
  // shfl partner: lane holding pooled channel (2l+2) with 8-group wrap
  const int src = (l & ~3) | ((l + 1) & 3);

  __syncthreads();

  for (int i = w; i < NBIN; i += 8) {
    float2 a0 = make_float2(0.f, 0.f), a1 = a0, a2 = a0, a3 = a0;
#pragma unroll
    for (int s = 0; s < 4; ++s) {
      const int4   id = sIdx[i * 4 + s];
      const float4 wt = sW[i * 4 + s];
      const float2 a = ft[id.x + chanOff];
      const float2 b = ft[id.y + chanOff];
      const float2 c = ft[id.z + chanOff];
      const float2 d = ft[id.w + chanOff];
      a0.x = fmaf(wt.x, a.x, a0.x); a0.y = fmaf(wt.x, a.y, a0.y);
      a1.x = fmaf(wt.y, b.x, a1.x); a1.y = fmaf(wt.y, b.y, a1.y);
      a2.x = fmaf(wt.z, c.x, a2.x); a2.y = fmaf(wt.z, c.y, a2.y);
      a3.x = fmaf(wt.w, d.x, a3.x); a3.y = fmaf(wt.w, d.y, a3.y);
    }
    float2 acc;
    acc.x = (a0.x + a1.x) + (a2.x + a3.x);
    acc.y = (a0.y + a1.y) + (a2.y + a3.y);
    // orientation mix with static indices:
    //   res[c] = rv*pool[c] + lv*pool[next(c)] (next wraps inside 8-group)
    const float nxt = __shfl(acc.x, src, 64);
    float2 res;
    res.x = rv * acc.x + lv * acc.y;
    res.y = rv * acc.y + lv * nxt;
    obuf[i][l] = res;                      // ds_write_b64, free 2-way
  }

  __syncthreads();

  // copy-out with rotation remap; one contiguous 25088 B region per block
  const float* ob = (const float*)obuf;    // row stride 2*OB_LD floats
  float* outh = out + (size_t)k * PCH + (size_t)half * (CHALF * NBIN);
  for (int jj = t; jj < (CHALF * NBIN) / 4; jj += 512) {
    const int j = jj * 4;
    float4 v;
#pragma unroll
    for (int e = 0; e < 4; ++e) {
      const int je   = j + e;
      const int crel = je / NBIN;
      const int bb   = je - crel * NBIN;
      const int clds = (crel & ~7) | ((crel - ind0) & 7);
      (&v.x)[e] = ob[bb * (2 * OB_LD) + clds];
    }
    *(float4*)(outh + j) = v;
  }
}

// ---------------------------------------------------------------------------
// Fallback (NCHW, scalar) — used only if workspace is too small.
// ---------------------------------------------------------------------------
__global__ __launch_bounds__(256) void os2_rroialign_nchw(
    const float* __restrict__ ft, const float* __restrict__ rois,
    float* __restrict__ out) {
  __shared__ __align__(16) float outBuf[PCH];
  __shared__ int4   sIdx[NSAMP];
  __shared__ float4 sW[NSAMP];

  const int k = blockIdx.x;
  const int t = threadIdx.x;

  const float* roi = rois + (size_t)k * 6;
  const float th = roi[5];

  if (t < NSAMP) {
    const int   b  = (int)roi[0];
    const float cx = roi[1] * SCALE;
    const float cy = roi[2] * SCALE;
    const float rw = fmaxf(roi[3] * SCALE, 1.0f);
    const float rh = fmaxf(roi[4] * SCALE, 1.0f);
    const float binw = rw / (float)OUTS;
    const float binh = rh / (float)OUTS;
    const float cs = cosf(th);
    const float sn = sinf(th);
    const int bin = t >> 2;
    const int sub = t & 3;
    const int ph  = bin / 7;
    const int pw  = bin - ph * 7;
    const float fy = (float)ph + ((float)(sub >> 1) + 0.5f) * 0.5f;
    const float fx = (float)pw + ((float)(sub & 1)  + 0.5f) * 0.5f;
    const float yy = -rh * 0.5f + fy * binh;
    const float xx = -rw * 0.5f + fx * binw;
    float x = xx * cs - yy * sn + cx;
    float y = xx * sn + yy * cs + cy;
    const bool valid = (y >= -1.0f) && (y <= (float)H_) &&
                       (x >= -1.0f) && (x <= (float)W_);
    y = fminf(fmaxf(y, 0.0f), (float)(H_ - 1));
    x = fminf(fmaxf(x, 0.0f), (float)(W_ - 1));
    int y0 = (int)floorf(y); if (y0 > H_ - 1) y0 = H_ - 1;
    int x0 = (int)floorf(x); if (x0 > W_ - 1) x0 = W_ - 1;
    const int y1 = min(y0 + 1, H_ - 1);
    const int x1 = min(x0 + 1, W_ - 1);
    const float ly = y - (float)y0, lx = x - (float)x0;
    const float hy = 1.0f - ly,     hx = 1.0f - lx;
    const float m  = valid ? 0.25f : 0.0f;
    sW[t] = make_float4(hy * hx * m, hy * lx * m, ly * hx * m, ly * lx * m);
    const int cb = b * C_TOT * H_ * W_;
    sIdx[t] = make_int4(cb + y0 * W_ + x0, cb + y0 * W_ + x1,
                        cb + y1 * W_ + x0, cb + y1 * W_ + x1);
  }

  const float indf = th * 1.27323954473516268615f;
  const float i0f  = floorf(indf);
  const float lv   = indf - i0f;
  const float rv   = 1.0f - lv;
  const int ind0 = ((int)i0f) & 7;
  const int o    = t & 7;
  const int ir   = (o - ind0) & 7;
  const int irp  = (ir + 1) & 7;
  const int grp  = t & 56;
  const int chanOff = t * (H_ * W_);

  __syncthreads();

  for (int bin = 0; bin < NBIN; ++bin) {
    float acc = 0.0f;
#pragma unroll
    for (int s = 0; s < 4; ++s) {
      const int4   id = sIdx[bin * 4 + s];
      const float4 w  = sW[bin * 4 + s];
      acc = fmaf(w.x, ft[id.x + chanOff], acc);
      acc = fmaf(w.y, ft[id.y + chanOff], acc);
      acc = fmaf(w.z, ft[id.z + chanOff], acc);
      acc = fmaf(w.w, ft[id.w + chanOff], acc);
    }
    const float v1 = __shfl(acc, grp | ir,  64);
    const float v2 = __shfl(acc, grp | irp, 64);
    outBuf[t * NBIN + bin] = rv * v1 + lv * v2;
  }

  __syncthreads();
  const float4* ob4 = (const float4*)outBuf;
  float4* o4 = (float4*)(out + (size_t)k * PCH);
#pragma unroll 4
  for (int j = t; j < PCH / 4; j += 256) o4[j] = ob4[j];
}

// ---------------------------------------------------------------------------
extern "C" void kernel_launch(void* const* d_in, const int* in_sizes, int n_in,
                              void* d_out, int out_size, void* d_ws, size_t ws_size,
                              hipStream_t stream) {
  const float* features = (const float*)d_in[0];
  const float* rois     = (const float*)d_in[1];
  float* out            = (float*)d_out;
  const int K = in_sizes[1] / 6;

  const size_t ftBytes = (size_t)N_ * C_TOT * H_ * W_ * sizeof(float);
  if (ws_size >= ftBytes) {
    float* ftT = (float*)d_ws;
    dim3 tb(64, 4);
    dim3 tg(W_ / 64, C_TOT / 64, N_ * H_);
    transpose_nchw_nhwc<<<tg, tb, 0, stream>>>(features, ftT);
    dim3 grid(K, 2);
    os2_rroialign_v4<<<grid, 512, 0, stream>>>((const float2*)ftT, rois, out);
  } else {
    os2_rroialign_nchw<<<K, 256, 0, stream>>>(features, rois, out);
  }
}

// Round 5
// 53.750 us; speedup vs baseline: 1.5373x; 1.2881x over previous
//
#include <hip/hip_runtime.h>
#include <hip/hip_bf16.h>
#include <hip/hip_fp16.h>
#include <math.h>

// Problem constants
constexpr int N_    = 2;
constexpr int C_TOT = 256;
constexpr int H_    = 128;
constexpr int W_    = 128;
constexpr int OUTS  = 7;
constexpr int NBIN  = OUTS * OUTS;          // 49
constexpr int NSAMP = NBIN * 4;             // 196 sample points per roi
constexpr int PCH   = C_TOT * NBIN;         // 12544 outputs per roi
constexpr float SCALE = 0.125f;
constexpr int OB_LD = C_TOT / 4 + 1;        // 65 uint2 (4 fp16 ch) per obuf row

__device__ __forceinline__ float2 h2f2(unsigned u) {
  __half2 h = *reinterpret_cast<__half2*>(&u);
  return __half22float2(h);
}

// ---------------------------------------------------------------------------
// NCHW f32 -> NHWC fp16 transpose of features into workspace.
// ---------------------------------------------------------------------------
__global__ __launch_bounds__(256) void transpose_nchw_nhwc_f16(
    const float* __restrict__ in, ushort* __restrict__ out) {
  __shared__ float tile[64][65];
  const int nh = blockIdx.z;
  const int n  = nh >> 7;
  const int h  = nh & 127;
  const int c0 = blockIdx.y * 64;
  const int w0 = blockIdx.x * 64;
  const int tx = threadIdx.x;
  const int ty = threadIdx.y;

  const float* src = in + (((size_t)n * C_TOT + c0) * H_ + h) * W_ + w0;
#pragma unroll
  for (int i = 0; i < 16; ++i) {
    const int c = i * 4 + ty;
    tile[c][tx] = src[(size_t)c * (H_ * W_) + tx];   // tile[c][w]
  }
  __syncthreads();
  // lane tx = channel (consecutive ushort): 128 B per wave-store, full lines
  ushort* dst = out + (((size_t)n * H_ + h) * W_ + w0) * C_TOT + c0;
#pragma unroll
  for (int i = 0; i < 16; ++i) {
    const int w = i * 4 + ty;
    dst[(size_t)w * C_TOT + tx] = __half_as_ushort(__float2half(tile[tx][w]));
  }
}

// ---------------------------------------------------------------------------
// v5 main kernel. Grid = K; 512 threads = 8 waves; 4 blocks/CU (100% occ).
//  - features fp16 NHWC: lane l owns channels 4l..4l+3 (one uint2 = 8 B);
//    a wave covers all 256 channels of a corner in 512 B = 4 cache lines
//    (halves the L2 line count vs f32 — the R3 bottleneck)
//  - fp16 obuf [bin][ch] (25.4 KB) -> LDS 31.8 KB
//  - 2 partial accumulator sets, orientation mix with static reg indices
//    (__shfl_xor(.,1) supplies the 8-group wrap), rotation remap at copy-out
// ---------------------------------------------------------------------------
__global__ __launch_bounds__(512, 8) void os2_rroialign_v5(
    const uint2* __restrict__ ft, const float* __restrict__ rois,
    float* __restrict__ out) {
  __shared__ uint2  obuf[NBIN][OB_LD];     // 49*65*8 = 25480 B (fp16 x4)
  __shared__ int4   sIdx[NSAMP];           // 3136 B (uint2-unit pixel base)
  __shared__ float4 sW[NSAMP];             // 3136 B

  const int k = blockIdx.x;
  const int t = threadIdx.x;

  const float* roi = rois + (size_t)k * 6;
  const float th = roi[5];

  if (t < NSAMP) {
    const int   b  = (int)roi[0];
    const float cx = roi[1] * SCALE;
    const float cy = roi[2] * SCALE;
    const float rw = fmaxf(roi[3] * SCALE, 1.0f);
    const float rh = fmaxf(roi[4] * SCALE, 1.0f);
    const float binw = rw / (float)OUTS;
    const float binh = rh / (float)OUTS;
    const float cs = cosf(th);
    const float sn = sinf(th);

    const int bin = t >> 2;
    const int sub = t & 3;                  // iy*2 + ix
    const int ph  = bin / 7;
    const int pw  = bin - ph * 7;
    const float fy = (float)ph + ((float)(sub >> 1) + 0.5f) * 0.5f;
    const float fx = (float)pw + ((float)(sub & 1)  + 0.5f) * 0.5f;
    const float yy = -rh * 0.5f + fy * binh;
    const float xx = -rw * 0.5f + fx * binw;
    float x = xx * cs - yy * sn + cx;
    float y = xx * sn + yy * cs + cy;
    const bool valid = (y >= -1.0f) && (y <= (float)H_) &&
                       (x >= -1.0f) && (x <= (float)W_);
    y = fminf(fmaxf(y, 0.0f), (float)(H_ - 1));
    x = fminf(fmaxf(x, 0.0f), (float)(W_ - 1));
    int y0 = (int)floorf(y); if (y0 > H_ - 1) y0 = H_ - 1;
    int x0 = (int)floorf(x); if (x0 > W_ - 1) x0 = W_ - 1;
    const int y1 = min(y0 + 1, H_ - 1);
    const int x1 = min(x0 + 1, W_ - 1);
    const float ly = y - (float)y0, lx = x - (float)x0;
    const float hy = 1.0f - ly,     hx = 1.0f - lx;
    const float m  = valid ? 0.25f : 0.0f;
    sW[t] = make_float4(hy * hx * m, hy * lx * m, ly * hx * m, ly * lx * m);
    const int pb = b * (H_ * W_);
    // offsets in uint2 units: pixel * (C_TOT/4)
    sIdx[t] = make_int4((pb + y0 * W_ + x0) * (C_TOT / 4),
                        (pb + y0 * W_ + x1) * (C_TOT / 4),
                        (pb + y1 * W_ + x0) * (C_TOT / 4),
                        (pb + y1 * W_ + x1) * (C_TOT / 4));
  }

  // orientation params (block-uniform)
  const float indf = th * 1.27323954473516268615f;   // * 8 / (2*pi)
  const float i0f  = floorf(indf);
  const float lv   = indf - i0f;
  const float rv   = 1.0f - lv;
  const int ind0 = __builtin_amdgcn_readfirstlane(((int)i0f) & 7);

  const int w = t >> 6;                    // wave id 0..7
  const int l = t & 63;                    // lane: channels 4l..4l+3

  __syncthreads();

  for (int i = w; i < NBIN; i += 8) {
    float4 p0 = make_float4(0.f, 0.f, 0.f, 0.f), p1 = p0;
#pragma unroll
    for (int s = 0; s < 4; ++s) {
      const int4   id = sIdx[i * 4 + s];
      const float4 wt = sW[i * 4 + s];
      const uint2 ua = ft[id.x + l];
      const uint2 ub = ft[id.y + l];
      const uint2 uc = ft[id.z + l];
      const uint2 ud = ft[id.w + l];
      const float2 a01 = h2f2(ua.x), a23 = h2f2(ua.y);
      const float2 b01 = h2f2(ub.x), b23 = h2f2(ub.y);
      const float2 c01 = h2f2(uc.x), c23 = h2f2(uc.y);
      const float2 d01 = h2f2(ud.x), d23 = h2f2(ud.y);
      p0.x = fmaf(wt.x, a01.x, p0.x); p0.y = fmaf(wt.x, a01.y, p0.y);
      p0.z = fmaf(wt.x, a23.x, p0.z); p0.w = fmaf(wt.x, a23.y, p0.w);
      p1.x = fmaf(wt.y, b01.x, p1.x); p1.y = fmaf(wt.y, b01.y, p1.y);
      p1.z = fmaf(wt.y, b23.x, p1.z); p1.w = fmaf(wt.y, b23.y, p1.w);
      p0.x = fmaf(wt.z, c01.x, p0.x); p0.y = fmaf(wt.z, c01.y, p0.y);
      p0.z = fmaf(wt.z, c23.x, p0.z); p0.w = fmaf(wt.z, c23.y, p0.w);
      p1.x = fmaf(wt.w, d01.x, p1.x); p1.y = fmaf(wt.w, d01.y, p1.y);
      p1.z = fmaf(wt.w, d23.x, p1.z); p1.w = fmaf(wt.w, d23.y, p1.w);
    }
    float4 tt;
    tt.x = p0.x + p1.x; tt.y = p0.y + p1.y;
    tt.z = p0.z + p1.z; tt.w = p0.w + p1.w;
    // orientation mix: res[c] = rv*pool[c] + lv*pool[next(c)]; channel 4l+3's
    // successor (with 8-group wrap) is lane (l^1)'s element 0 in all cases.
    const float nxt = __shfl_xor(tt.x, 1);
    float4 res;
    res.x = rv * tt.x + lv * tt.y;
    res.y = rv * tt.y + lv * tt.z;
    res.z = rv * tt.z + lv * tt.w;
    res.w = rv * tt.w + lv * nxt;
    const __half2 h01 = __floats2half2_rn(res.x, res.y);
    const __half2 h23 = __floats2half2_rn(res.z, res.w);
    uint2 pk;
    pk.x = *reinterpret_cast<const unsigned*>(&h01);
    pk.y = *reinterpret_cast<const unsigned*>(&h23);
    obuf[i][l] = pk;                       // ds_write_b64, 2-way (free)
  }

  __syncthreads();

  // copy-out with rotation remap; one contiguous 49 KB region per block
  const __half* ob = (const __half*)obuf;  // row stride 4*OB_LD halves
  float* outk = out + (size_t)k * PCH;
  for (int j4 = t; j4 < PCH / 4; j4 += 512) {
    const int j = j4 * 4;
    float4 v;
#pragma unroll
    for (int e = 0; e < 4; ++e) {
      const int je   = j + e;
      const int cout = je / NBIN;
      const int bb   = je - cout * NBIN;
      const int clds = (cout & ~7) | ((cout - ind0) & 7);
      (&v.x)[e] = __half2float(ob[bb * (4 * OB_LD) + clds]);
    }
    *(float4*)(outk + j) = v;
  }
}

// ---------------------------------------------------------------------------
// Fallback (NCHW f32, scalar) — used only if workspace is too small.
// ---------------------------------------------------------------------------
__global__ __launch_bounds__(256) void os2_rroialign_nchw(
    const float* __restrict__ ft, const float* __restrict__ rois,
    float* __restrict__ out) {
  __shared__ __align__(16) float outBuf[PCH];
  __shared__ int4   sIdx[NSAMP];
  __shared__ float4 sW[NSAMP];

  const int k = blockIdx.x;
  const int t = threadIdx.x;

  const float* roi = rois + (size_t)k * 6;
  const float th = roi[5];

  if (t < NSAMP) {
    const int   b  = (int)roi[0];
    const float cx = roi[1] * SCALE;
    const float cy = roi[2] * SCALE;
    const float rw = fmaxf(roi[3] * SCALE, 1.0f);
    const float rh = fmaxf(roi[4] * SCALE, 1.0f);
    const float binw = rw / (float)OUTS;
    const float binh = rh / (float)OUTS;
    const float cs = cosf(th);
    const float sn = sinf(th);
    const int bin = t >> 2;
    const int sub = t & 3;
    const int ph  = bin / 7;
    const int pw  = bin - ph * 7;
    const float fy = (float)ph + ((float)(sub >> 1) + 0.5f) * 0.5f;
    const float fx = (float)pw + ((float)(sub & 1)  + 0.5f) * 0.5f;
    const float yy = -rh * 0.5f + fy * binh;
    const float xx = -rw * 0.5f + fx * binw;
    float x = xx * cs - yy * sn + cx;
    float y = xx * sn + yy * cs + cy;
    const bool valid = (y >= -1.0f) && (y <= (float)H_) &&
                       (x >= -1.0f) && (x <= (float)W_);
    y = fminf(fmaxf(y, 0.0f), (float)(H_ - 1));
    x = fminf(fmaxf(x, 0.0f), (float)(W_ - 1));
    int y0 = (int)floorf(y); if (y0 > H_ - 1) y0 = H_ - 1;
    int x0 = (int)floorf(x); if (x0 > W_ - 1) x0 = W_ - 1;
    const int y1 = min(y0 + 1, H_ - 1);
    const int x1 = min(x0 + 1, W_ - 1);
    const float ly = y - (float)y0, lx = x - (float)x0;
    const float hy = 1.0f - ly,     hx = 1.0f - lx;
    const float m  = valid ? 0.25f : 0.0f;
    sW[t] = make_float4(hy * hx * m, hy * lx * m, ly * hx * m, ly * lx * m);
    const int cb = b * C_TOT * H_ * W_;
    sIdx[t] = make_int4(cb + y0 * W_ + x0, cb + y0 * W_ + x1,
                        cb + y1 * W_ + x0, cb + y1 * W_ + x1);
  }

  const float indf = th * 1.27323954473516268615f;
  const float i0f  = floorf(indf);
  const float lv   = indf - i0f;
  const float rv   = 1.0f - lv;
  const int ind0 = ((int)i0f) & 7;
  const int o    = t & 7;
  const int ir   = (o - ind0) & 7;
  const int irp  = (ir + 1) & 7;
  const int grp  = t & 56;
  const int chanOff = t * (H_ * W_);

  __syncthreads();

  for (int bin = 0; bin < NBIN; ++bin) {
    float acc = 0.0f;
#pragma unroll
    for (int s = 0; s < 4; ++s) {
      const int4   id = sIdx[bin * 4 + s];
      const float4 w  = sW[bin * 4 + s];
      acc = fmaf(w.x, ft[id.x + chanOff], acc);
      acc = fmaf(w.y, ft[id.y + chanOff], acc);
      acc = fmaf(w.z, ft[id.z + chanOff], acc);
      acc = fmaf(w.w, ft[id.w + chanOff], acc);
    }
    const float v1 = __shfl(acc, grp | ir,  64);
    const float v2 = __shfl(acc, grp | irp, 64);
    outBuf[t * NBIN + bin] = rv * v1 + lv * v2;
  }

  __syncthreads();
  const float4* ob4 = (const float4*)outBuf;
  float4* o4 = (float4*)(out + (size_t)k * PCH);
#pragma unroll 4
  for (int j = t; j < PCH / 4; j += 256) o4[j] = ob4[j];
}

// ---------------------------------------------------------------------------
extern "C" void kernel_launch(void* const* d_in, const int* in_sizes, int n_in,
                              void* d_out, int out_size, void* d_ws, size_t ws_size,
                              hipStream_t stream) {
  const float* features = (const float*)d_in[0];
  const float* rois     = (const float*)d_in[1];
  float* out            = (float*)d_out;
  const int K = in_sizes[1] / 6;

  const size_t ftBytes = (size_t)N_ * C_TOT * H_ * W_ * sizeof(ushort);
  if (ws_size >= ftBytes) {
    ushort* ftT = (ushort*)d_ws;
    dim3 tb(64, 4);
    dim3 tg(W_ / 64, C_TOT / 64, N_ * H_);
    transpose_nchw_nhwc_f16<<<tg, tb, 0, stream>>>(features, ftT);
    os2_rroialign_v5<<<K, 512, 0, stream>>>((const uint2*)ftT, rois, out);
  } else {
    os2_rroialign_nchw<<<K, 256, 0, stream>>>(features, rois, out);
  }
}

// Round 7
// 45.265 us; speedup vs baseline: 1.8255x; 1.1874x over previous
//
#include <hip/hip_runtime.h>
#include <hip/hip_bf16.h>
#include <hip/hip_fp16.h>
#include <math.h>

// Problem constants
constexpr int N_    = 2;
constexpr int C_TOT = 256;
constexpr int H_    = 128;
constexpr int W_    = 128;
constexpr int OUTS  = 7;
constexpr int NBIN  = OUTS * OUTS;          // 49
constexpr int NSAMP = NBIN * 4;             // 196 sample points per roi
constexpr int PCH   = C_TOT * NBIN;         // 12544 outputs per roi
constexpr float SCALE = 0.125f;
constexpr int OB_LD = C_TOT / 4 + 1;        // 65 uint2 (4 fp16 ch) per obuf row

typedef float f32x4 __attribute__((ext_vector_type(4)));   // native vec for
                                                           // nontemporal store

__device__ __forceinline__ __half2 u2h2(unsigned u) {
  return *reinterpret_cast<__half2*>(&u);
}
__device__ __forceinline__ unsigned h2u(__half2 h) {
  return *reinterpret_cast<unsigned*>(&h);
}

// ---------------------------------------------------------------------------
// NCHW f32 -> NHWC fp16 transpose of features into workspace.
// ---------------------------------------------------------------------------
__global__ __launch_bounds__(256) void transpose_nchw_nhwc_f16(
    const float* __restrict__ in, ushort* __restrict__ out) {
  __shared__ float tile[64][65];
  const int nh = blockIdx.z;
  const int n  = nh >> 7;
  const int h  = nh & 127;
  const int c0 = blockIdx.y * 64;
  const int w0 = blockIdx.x * 64;
  const int tx = threadIdx.x;
  const int ty = threadIdx.y;

  const float* src = in + (((size_t)n * C_TOT + c0) * H_ + h) * W_ + w0;
#pragma unroll
  for (int i = 0; i < 16; ++i) {
    const int c = i * 4 + ty;
    tile[c][tx] = src[(size_t)c * (H_ * W_) + tx];
  }
  __syncthreads();
  ushort* dst = out + (((size_t)n * H_ + h) * W_ + w0) * C_TOT + c0;
#pragma unroll
  for (int i = 0; i < 16; ++i) {
    const int w = i * 4 + ty;
    dst[(size_t)w * C_TOT + tx] = __half_as_ushort(__float2half(tile[tx][w]));
  }
}

// ---------------------------------------------------------------------------
// v6 main kernel. Grid = K; 512 threads = 8 waves; 4 blocks/CU.
//  - features fp16 NHWC: lane l owns channels 4l..4l+3 (one uint2 = 8 B);
//    a wave covers all 256 channels of a corner in 512 B = 4 cache lines
//  - gather loop accumulates in PACKED fp16 (v_pk_fma_f16 via __hfma2):
//    8 pk_fma per sample-point replaces 16 cvt + 16 f32 fma (R4 bottleneck)
//  - weights staged in LDS as duplicated-half2 (uint4 per sample point)
//  - 4 accumulators (2 corner-groups x 2 ch-pairs): fp16 add-chain depth 4
//  - f32 conversion once per bin for the orientation mix; fp16 obuf staging;
//    rotation remap at copy-out; nontemporal final stores
// ---------------------------------------------------------------------------
__global__ __launch_bounds__(512, 8) void os2_rroialign_v6(
    const uint2* __restrict__ ft, const float* __restrict__ rois,
    float* __restrict__ out) {
  __shared__ uint2 obuf[NBIN][OB_LD];      // 49*65*8 = 25480 B (fp16 x4)
  __shared__ int4  sIdx[NSAMP];            // 3136 B (uint2-unit pixel base)
  __shared__ uint4 sWh[NSAMP];             // 3136 B (4 dup-half2 weights)

  const int k = blockIdx.x;
  const int t = threadIdx.x;

  const float* roi = rois + (size_t)k * 6;
  const float th = roi[5];

  if (t < NSAMP) {
    const int   b  = (int)roi[0];
    const float cx = roi[1] * SCALE;
    const float cy = roi[2] * SCALE;
    const float rw = fmaxf(roi[3] * SCALE, 1.0f);
    const float rh = fmaxf(roi[4] * SCALE, 1.0f);
    const float binw = rw / (float)OUTS;
    const float binh = rh / (float)OUTS;
    const float cs = cosf(th);
    const float sn = sinf(th);

    const int bin = t >> 2;
    const int sub = t & 3;                  // iy*2 + ix
    const int ph  = bin / 7;
    const int pw  = bin - ph * 7;
    const float fy = (float)ph + ((float)(sub >> 1) + 0.5f) * 0.5f;
    const float fx = (float)pw + ((float)(sub & 1)  + 0.5f) * 0.5f;
    const float yy = -rh * 0.5f + fy * binh;
    const float xx = -rw * 0.5f + fx * binw;
    float x = xx * cs - yy * sn + cx;
    float y = xx * sn + yy * cs + cy;
    const bool valid = (y >= -1.0f) && (y <= (float)H_) &&
                       (x >= -1.0f) && (x <= (float)W_);
    y = fminf(fmaxf(y, 0.0f), (float)(H_ - 1));
    x = fminf(fmaxf(x, 0.0f), (float)(W_ - 1));
    int y0 = (int)floorf(y); if (y0 > H_ - 1) y0 = H_ - 1;
    int x0 = (int)floorf(x); if (x0 > W_ - 1) x0 = W_ - 1;
    const int y1 = min(y0 + 1, H_ - 1);
    const int x1 = min(x0 + 1, W_ - 1);
    const float ly = y - (float)y0, lx = x - (float)x0;
    const float hy = 1.0f - ly,     hx = 1.0f - lx;
    const float m  = valid ? 0.25f : 0.0f;
    const __half2 wa = __float2half2_rn(hy * hx * m);
    const __half2 wb = __float2half2_rn(hy * lx * m);
    const __half2 wc = __float2half2_rn(ly * hx * m);
    const __half2 wd = __float2half2_rn(ly * lx * m);
    uint4 pw4;
    pw4.x = h2u(wa); pw4.y = h2u(wb); pw4.z = h2u(wc); pw4.w = h2u(wd);
    sWh[t] = pw4;
    const int pb = b * (H_ * W_);
    // offsets in uint2 units: pixel * (C_TOT/4)
    sIdx[t] = make_int4((pb + y0 * W_ + x0) * (C_TOT / 4),
                        (pb + y0 * W_ + x1) * (C_TOT / 4),
                        (pb + y1 * W_ + x0) * (C_TOT / 4),
                        (pb + y1 * W_ + x1) * (C_TOT / 4));
  }

  // orientation params (block-uniform)
  const float indf = th * 1.27323954473516268615f;   // * 8 / (2*pi)
  const float i0f  = floorf(indf);
  const float lv   = indf - i0f;
  const float rv   = 1.0f - lv;
  const int ind0 = __builtin_amdgcn_readfirstlane(((int)i0f) & 7);

  const int w = t >> 6;                    // wave id 0..7
  const int l = t & 63;                    // lane: channels 4l..4l+3

  __syncthreads();

  const __half2 zero = __float2half2_rn(0.0f);

  for (int i = w; i < NBIN; i += 8) {
    // fp16 packed accumulators: {corner-group 0 (a,c), group 1 (b,d)} x
    // {ch pair 01, ch pair 23}; chain depth 4 each
    __half2 g0p01 = zero, g0p23 = zero, g1p01 = zero, g1p23 = zero;
#pragma unroll
    for (int s = 0; s < 4; ++s) {
      const int4  id = sIdx[i * 4 + s];
      const uint4 wt = sWh[i * 4 + s];
      const uint2 ua = ft[id.x + l];
      const uint2 ub = ft[id.y + l];
      const uint2 uc = ft[id.z + l];
      const uint2 ud = ft[id.w + l];
      g0p01 = __hfma2(u2h2(ua.x), u2h2(wt.x), g0p01);
      g0p23 = __hfma2(u2h2(ua.y), u2h2(wt.x), g0p23);
      g1p01 = __hfma2(u2h2(ub.x), u2h2(wt.y), g1p01);
      g1p23 = __hfma2(u2h2(ub.y), u2h2(wt.y), g1p23);
      g0p01 = __hfma2(u2h2(uc.x), u2h2(wt.z), g0p01);
      g0p23 = __hfma2(u2h2(uc.y), u2h2(wt.z), g0p23);
      g1p01 = __hfma2(u2h2(ud.x), u2h2(wt.w), g1p01);
      g1p23 = __hfma2(u2h2(ud.y), u2h2(wt.w), g1p23);
    }
    // to f32 once per bin
    const float2 f01a = __half22float2(g0p01), f01b = __half22float2(g1p01);
    const float2 f23a = __half22float2(g0p23), f23b = __half22float2(g1p23);
    float4 tt;
    tt.x = f01a.x + f01b.x; tt.y = f01a.y + f01b.y;
    tt.z = f23a.x + f23b.x; tt.w = f23a.y + f23b.y;
    // orientation mix: res[c] = rv*pool[c] + lv*pool[next(c)]; channel 4l+3's
    // successor (8-group wrap) is lane (l^1)'s element 0.
    const float nxt = __shfl_xor(tt.x, 1);
    float4 res;
    res.x = rv * tt.x + lv * tt.y;
    res.y = rv * tt.y + lv * tt.z;
    res.z = rv * tt.z + lv * tt.w;
    res.w = rv * tt.w + lv * nxt;
    uint2 pk;
    pk.x = h2u(__floats2half2_rn(res.x, res.y));
    pk.y = h2u(__floats2half2_rn(res.z, res.w));
    obuf[i][l] = pk;                       // ds_write_b64, 2-way (free)
  }

  __syncthreads();

  // copy-out with rotation remap; contiguous 49 KB per block, nontemporal
  const __half* ob = (const __half*)obuf;  // row stride 4*OB_LD halves
  float* outk = out + (size_t)k * PCH;
  for (int j4 = t; j4 < PCH / 4; j4 += 512) {
    const int j = j4 * 4;
    f32x4 v;
#pragma unroll
    for (int e = 0; e < 4; ++e) {
      const int je   = j + e;
      const int cout = je / NBIN;
      const int bb   = je - cout * NBIN;
      const int clds = (cout & ~7) | ((cout - ind0) & 7);
      v[e] = __half2float(ob[bb * (4 * OB_LD) + clds]);
    }
    __builtin_nontemporal_store(v, (f32x4*)(outk + j));
  }
}

// ---------------------------------------------------------------------------
// Fallback (NCHW f32, scalar) — used only if workspace is too small.
// ---------------------------------------------------------------------------
__global__ __launch_bounds__(256) void os2_rroialign_nchw(
    const float* __restrict__ ft, const float* __restrict__ rois,
    float* __restrict__ out) {
  __shared__ __align__(16) float outBuf[PCH];
  __shared__ int4   sIdx[NSAMP];
  __shared__ float4 sW[NSAMP];

  const int k = blockIdx.x;
  const int t = threadIdx.x;

  const float* roi = rois + (size_t)k * 6;
  const float th = roi[5];

  if (t < NSAMP) {
    const int   b  = (int)roi[0];
    const float cx = roi[1] * SCALE;
    const float cy = roi[2] * SCALE;
    const float rw = fmaxf(roi[3] * SCALE, 1.0f);
    const float rh = fmaxf(roi[4] * SCALE, 1.0f);
    const float binw = rw / (float)OUTS;
    const float binh = rh / (float)OUTS;
    const float cs = cosf(th);
    const float sn = sinf(th);
    const int bin = t >> 2;
    const int sub = t & 3;
    const int ph  = bin / 7;
    const int pw  = bin - ph * 7;
    const float fy = (float)ph + ((float)(sub >> 1) + 0.5f) * 0.5f;
    const float fx = (float)pw + ((float)(sub & 1)  + 0.5f) * 0.5f;
    const float yy = -rh * 0.5f + fy * binh;
    const float xx = -rw * 0.5f + fx * binw;
    float x = xx * cs - yy * sn + cx;
    float y = xx * sn + yy * cs + cy;
    const bool valid = (y >= -1.0f) && (y <= (float)H_) &&
                       (x >= -1.0f) && (x <= (float)W_);
    y = fminf(fmaxf(y, 0.0f), (float)(H_ - 1));
    x = fminf(fmaxf(x, 0.0f), (float)(W_ - 1));
    int y0 = (int)floorf(y); if (y0 > H_ - 1) y0 = H_ - 1;
    int x0 = (int)floorf(x); if (x0 > W_ - 1) x0 = W_ - 1;
    const int y1 = min(y0 + 1, H_ - 1);
    const int x1 = min(x0 + 1, W_ - 1);
    const float ly = y - (float)y0, lx = x - (float)x0;
    const float hy = 1.0f - ly,     hx = 1.0f - lx;
    const float m  = valid ? 0.25f : 0.0f;
    sW[t] = make_float4(hy * hx * m, hy * lx * m, ly * hx * m, ly * lx * m);
    const int cb = b * C_TOT * H_ * W_;
    sIdx[t] = make_int4(cb + y0 * W_ + x0, cb + y0 * W_ + x1,
                        cb + y1 * W_ + x0, cb + y1 * W_ + x1);
  }

  const float indf = th * 1.27323954473516268615f;
  const float i0f  = floorf(indf);
  const float lv   = indf - i0f;
  const float rv   = 1.0f - lv;
  const int ind0 = ((int)i0f) & 7;
  const int o    = t & 7;
  const int ir   = (o - ind0) & 7;
  const int irp  = (ir + 1) & 7;
  const int grp  = t & 56;
  const int chanOff = t * (H_ * W_);

  __syncthreads();

  for (int bin = 0; bin < NBIN; ++bin) {
    float acc = 0.0f;
#pragma unroll
    for (int s = 0; s < 4; ++s) {
      const int4   id = sIdx[bin * 4 + s];
      const float4 w  = sW[bin * 4 + s];
      acc = fmaf(w.x, ft[id.x + chanOff], acc);
      acc = fmaf(w.y, ft[id.y + chanOff], acc);
      acc = fmaf(w.z, ft[id.z + chanOff], acc);
      acc = fmaf(w.w, ft[id.w + chanOff], acc);
    }
    const float v1 = __shfl(acc, grp | ir,  64);
    const float v2 = __shfl(acc, grp | irp, 64);
    outBuf[t * NBIN + bin] = rv * v1 + lv * v2;
  }

  __syncthreads();
  const float4* ob4 = (const float4*)outBuf;
  float4* o4 = (float4*)(out + (size_t)k * PCH);
#pragma unroll 4
  for (int j = t; j < PCH / 4; j += 256) o4[j] = ob4[j];
}

// ---------------------------------------------------------------------------
extern "C" void kernel_launch(void* const* d_in, const int* in_sizes, int n_in,
                              void* d_out, int out_size, void* d_ws, size_t ws_size,
                              hipStream_t stream) {
  const float* features = (const float*)d_in[0];
  const float* rois     = (const float*)d_in[1];
  float* out            = (float*)d_out;
  const int K = in_sizes[1] / 6;

  const size_t ftBytes = (size_t)N_ * C_TOT * H_ * W_ * sizeof(ushort);
  if (ws_size >= ftBytes) {
    ushort* ftT = (ushort*)d_ws;
    dim3 tb(64, 4);
    dim3 tg(W_ / 64, C_TOT / 64, N_ * H_);
    transpose_nchw_nhwc_f16<<<tg, tb, 0, stream>>>(features, ftT);
    os2_rroialign_v6<<<K, 512, 0, stream>>>((const uint2*)ftT, rois, out);
  } else {
    os2_rroialign_nchw<<<K, 256, 0, stream>>>(features, rois, out);
  }
}

// Round 8
// 43.543 us; speedup vs baseline: 1.8977x; 1.0395x over previous
//
#include <hip/hip_runtime.h>
#include <hip/hip_bf16.h>
#include <hip/hip_fp16.h>
#include <math.h>

// Problem constants
constexpr int N_    = 2;
constexpr int C_TOT = 256;
constexpr int H_    = 128;
constexpr int W_    = 128;
constexpr int OUTS  = 7;
constexpr int NBIN  = OUTS * OUTS;          // 49
constexpr int NSAMP = NBIN * 4;             // 196 sample points per roi
constexpr int PCH   = C_TOT * NBIN;         // 12544 outputs per roi
constexpr float SCALE = 0.125f;
constexpr int OB_LD = C_TOT / 4 + 1;        // 65 uint2 (4 fp16 ch) per obuf row

typedef float f32x4 __attribute__((ext_vector_type(4)));

__device__ __forceinline__ __half2 u2h2(unsigned u) {
  return *reinterpret_cast<__half2*>(&u);
}
__device__ __forceinline__ unsigned h2u(__half2 h) {
  return *reinterpret_cast<unsigned*>(&h);
}

// ---------------------------------------------------------------------------
// NCHW f32 -> NHWC fp16 transpose of features into workspace.
// ---------------------------------------------------------------------------
__global__ __launch_bounds__(256) void transpose_nchw_nhwc_f16(
    const float* __restrict__ in, ushort* __restrict__ out) {
  __shared__ float tile[64][65];
  const int nh = blockIdx.z;
  const int n  = nh >> 7;
  const int h  = nh & 127;
  const int c0 = blockIdx.y * 64;
  const int w0 = blockIdx.x * 64;
  const int tx = threadIdx.x;
  const int ty = threadIdx.y;

  const float* src = in + (((size_t)n * C_TOT + c0) * H_ + h) * W_ + w0;
#pragma unroll
  for (int i = 0; i < 16; ++i) {
    const int c = i * 4 + ty;
    tile[c][tx] = src[(size_t)c * (H_ * W_) + tx];
  }
  __syncthreads();
  ushort* dst = out + (((size_t)n * H_ + h) * W_ + w0) * C_TOT + c0;
#pragma unroll
  for (int i = 0; i < 16; ++i) {
    const int w = i * 4 + ty;
    dst[(size_t)w * C_TOT + tx] = __half_as_ushort(__float2half(tile[tx][w]));
  }
}

// ---------------------------------------------------------------------------
// v7 main kernel. Grid = K; 512 threads = 8 waves; 4 blocks/CU.
//  - uint4 gathers (16 B/lane = 8 fp16 channels): lane l, cl = l&31 owns
//    channels 8cl..8cl+7; lanes 0-31 process corners {A=(y0,x0), C=(y1,x0)},
//    lanes 32-63 process {B=(y0,x1), D=(y1,x1)} via cndmask base/weight
//    selects. 8 wave-loads per bin (VMEM instruction floor) vs 16 in v6.
//  - corner-pair partials combined with 4 shfl_xor(32) + hadd2
//  - orientation 8-group = exactly one lane's 8 channels -> mix is fully
//    in-lane, zero shuffles
//  - fp16 obuf staging, rotation remap at copy-out, nontemporal stores
// ---------------------------------------------------------------------------
__global__ __launch_bounds__(512, 8) void os2_rroialign_v7(
    const uint4* __restrict__ ft, const float* __restrict__ rois,
    float* __restrict__ out) {
  __shared__ uint2 obuf[NBIN][OB_LD];      // 49*65*8 = 25480 B (fp16 x4)
  __shared__ int4  sIdx[NSAMP];            // 3136 B (uint4-unit pixel base)
  __shared__ uint4 sWh[NSAMP];             // 3136 B (4 dup-half2 weights)

  const int k = blockIdx.x;
  const int t = threadIdx.x;

  const float* roi = rois + (size_t)k * 6;
  const float th = roi[5];

  if (t < NSAMP) {
    const int   b  = (int)roi[0];
    const float cx = roi[1] * SCALE;
    const float cy = roi[2] * SCALE;
    const float rw = fmaxf(roi[3] * SCALE, 1.0f);
    const float rh = fmaxf(roi[4] * SCALE, 1.0f);
    const float binw = rw / (float)OUTS;
    const float binh = rh / (float)OUTS;
    const float cs = cosf(th);
    const float sn = sinf(th);

    const int bin = t >> 2;
    const int sub = t & 3;                  // iy*2 + ix
    const int ph  = bin / 7;
    const int pw  = bin - ph * 7;
    const float fy = (float)ph + ((float)(sub >> 1) + 0.5f) * 0.5f;
    const float fx = (float)pw + ((float)(sub & 1)  + 0.5f) * 0.5f;
    const float yy = -rh * 0.5f + fy * binh;
    const float xx = -rw * 0.5f + fx * binw;
    float x = xx * cs - yy * sn + cx;
    float y = xx * sn + yy * cs + cy;
    const bool valid = (y >= -1.0f) && (y <= (float)H_) &&
                       (x >= -1.0f) && (x <= (float)W_);
    y = fminf(fmaxf(y, 0.0f), (float)(H_ - 1));
    x = fminf(fmaxf(x, 0.0f), (float)(W_ - 1));
    int y0 = (int)floorf(y); if (y0 > H_ - 1) y0 = H_ - 1;
    int x0 = (int)floorf(x); if (x0 > W_ - 1) x0 = W_ - 1;
    const int y1 = min(y0 + 1, H_ - 1);
    const int x1 = min(x0 + 1, W_ - 1);
    const float ly = y - (float)y0, lx = x - (float)x0;
    const float hy = 1.0f - ly,     hx = 1.0f - lx;
    const float m  = valid ? 0.25f : 0.0f;
    const __half2 wa = __float2half2_rn(hy * hx * m);   // (y0,x0)
    const __half2 wb = __float2half2_rn(hy * lx * m);   // (y0,x1)
    const __half2 wc = __float2half2_rn(ly * hx * m);   // (y1,x0)
    const __half2 wd = __float2half2_rn(ly * lx * m);   // (y1,x1)
    uint4 pw4;
    pw4.x = h2u(wa); pw4.y = h2u(wb); pw4.z = h2u(wc); pw4.w = h2u(wd);
    sWh[t] = pw4;
    const int pb = b * (H_ * W_);
    // offsets in uint4 units: pixel * (C_TOT/8)
    sIdx[t] = make_int4((pb + y0 * W_ + x0) * (C_TOT / 8),
                        (pb + y0 * W_ + x1) * (C_TOT / 8),
                        (pb + y1 * W_ + x0) * (C_TOT / 8),
                        (pb + y1 * W_ + x1) * (C_TOT / 8));
  }

  // orientation params (block-uniform)
  const float indf = th * 1.27323954473516268615f;   // * 8 / (2*pi)
  const float i0f  = floorf(indf);
  const float lv   = indf - i0f;
  const float rv   = 1.0f - lv;
  const int ind0 = __builtin_amdgcn_readfirstlane(((int)i0f) & 7);

  const int w  = t >> 6;                   // wave id 0..7
  const int l  = t & 63;
  const int cl = l & 31;                   // channel group: ch 8cl..8cl+7
  const bool hiHalf = (l & 32) != 0;       // false: corners A,C; true: B,D

  __syncthreads();

  const __half2 zero = __float2half2_rn(0.0f);

  for (int i = w; i < NBIN; i += 8) {
    __half2 a01 = zero, a23 = zero, a45 = zero, a67 = zero;
#pragma unroll
    for (int s = 0; s < 4; ++s) {
      const int4  id = sIdx[i * 4 + s];
      const uint4 wt = sWh[i * 4 + s];
      const int b1 = hiHalf ? id.y : id.x;             // A | B
      const int b2 = hiHalf ? id.w : id.z;             // C | D
      const __half2 w1 = u2h2(hiHalf ? wt.y : wt.x);
      const __half2 w2 = u2h2(hiHalf ? wt.w : wt.z);
      const uint4 u1 = ft[b1 + cl];
      const uint4 u2 = ft[b2 + cl];
      a01 = __hfma2(u2h2(u1.x), w1, a01);
      a23 = __hfma2(u2h2(u1.y), w1, a23);
      a45 = __hfma2(u2h2(u1.z), w1, a45);
      a67 = __hfma2(u2h2(u1.w), w1, a67);
      a01 = __hfma2(u2h2(u2.x), w2, a01);
      a23 = __hfma2(u2h2(u2.y), w2, a23);
      a45 = __hfma2(u2h2(u2.z), w2, a45);
      a67 = __hfma2(u2h2(u2.w), w2, a67);
    }
    // combine corner-pair partials: lanes l and l^32 cover the same channels
    a01 = __hadd2(a01, u2h2(__shfl_xor(h2u(a01), 32)));
    a23 = __hadd2(a23, u2h2(__shfl_xor(h2u(a23), 32)));
    a45 = __hadd2(a45, u2h2(__shfl_xor(h2u(a45), 32)));
    a67 = __hadd2(a67, u2h2(__shfl_xor(h2u(a67), 32)));
    // 8 pooled channels fully in-lane: orientation mix needs no shuffles
    float p[8];
    float2 f;
    f = __half22float2(a01); p[0] = f.x; p[1] = f.y;
    f = __half22float2(a23); p[2] = f.x; p[3] = f.y;
    f = __half22float2(a45); p[4] = f.x; p[5] = f.y;
    f = __half22float2(a67); p[6] = f.x; p[7] = f.y;
    float r[8];
#pragma unroll
    for (int j = 0; j < 8; ++j) r[j] = rv * p[j] + lv * p[(j + 1) & 7];
    const unsigned q01 = h2u(__floats2half2_rn(r[0], r[1]));
    const unsigned q23 = h2u(__floats2half2_rn(r[2], r[3]));
    const unsigned q45 = h2u(__floats2half2_rn(r[4], r[5]));
    const unsigned q67 = h2u(__floats2half2_rn(r[6], r[7]));
    // half0 lanes write ch 8cl..+3, half1 lanes ch 8cl+4..+7 (ds_write_b64)
    uint2 pk;
    pk.x = hiHalf ? q45 : q01;
    pk.y = hiHalf ? q67 : q23;
    obuf[i][2 * cl + (hiHalf ? 1 : 0)] = pk;
  }

  __syncthreads();

  // copy-out with rotation remap; contiguous 49 KB per block, nontemporal
  const __half* ob = (const __half*)obuf;  // row stride 4*OB_LD halves
  float* outk = out + (size_t)k * PCH;
  for (int j4 = t; j4 < PCH / 4; j4 += 512) {
    const int j = j4 * 4;
    f32x4 v;
#pragma unroll
    for (int e = 0; e < 4; ++e) {
      const int je   = j + e;
      const int cout = je / NBIN;
      const int bb   = je - cout * NBIN;
      const int clds = (cout & ~7) | ((cout - ind0) & 7);
      v[e] = __half2float(ob[bb * (4 * OB_LD) + clds]);
    }
    __builtin_nontemporal_store(v, (f32x4*)(outk + j));
  }
}

// ---------------------------------------------------------------------------
// Fallback (NCHW f32, scalar) — used only if workspace is too small.
// ---------------------------------------------------------------------------
__global__ __launch_bounds__(256) void os2_rroialign_nchw(
    const float* __restrict__ ft, const float* __restrict__ rois,
    float* __restrict__ out) {
  __shared__ __align__(16) float outBuf[PCH];
  __shared__ int4   sIdx[NSAMP];
  __shared__ float4 sW[NSAMP];

  const int k = blockIdx.x;
  const int t = threadIdx.x;

  const float* roi = rois + (size_t)k * 6;
  const float th = roi[5];

  if (t < NSAMP) {
    const int   b  = (int)roi[0];
    const float cx = roi[1] * SCALE;
    const float cy = roi[2] * SCALE;
    const float rw = fmaxf(roi[3] * SCALE, 1.0f);
    const float rh = fmaxf(roi[4] * SCALE, 1.0f);
    const float binw = rw / (float)OUTS;
    const float binh = rh / (float)OUTS;
    const float cs = cosf(th);
    const float sn = sinf(th);
    const int bin = t >> 2;
    const int sub = t & 3;
    const int ph  = bin / 7;
    const int pw  = bin - ph * 7;
    const float fy = (float)ph + ((float)(sub >> 1) + 0.5f) * 0.5f;
    const float fx = (float)pw + ((float)(sub & 1)  + 0.5f) * 0.5f;
    const float yy = -rh * 0.5f + fy * binh;
    const float xx = -rw * 0.5f + fx * binw;
    float x = xx * cs - yy * sn + cx;
    float y = xx * sn + yy * cs + cy;
    const bool valid = (y >= -1.0f) && (y <= (float)H_) &&
                       (x >= -1.0f) && (x <= (float)W_);
    y = fminf(fmaxf(y, 0.0f), (float)(H_ - 1));
    x = fminf(fmaxf(x, 0.0f), (float)(W_ - 1));
    int y0 = (int)floorf(y); if (y0 > H_ - 1) y0 = H_ - 1;
    int x0 = (int)floorf(x); if (x0 > W_ - 1) x0 = W_ - 1;
    const int y1 = min(y0 + 1, H_ - 1);
    const int x1 = min(x0 + 1, W_ - 1);
    const float ly = y - (float)y0, lx = x - (float)x0;
    const float hy = 1.0f - ly,     hx = 1.0f - lx;
    const float m  = valid ? 0.25f : 0.0f;
    sW[t] = make_float4(hy * hx * m, hy * lx * m, ly * hx * m, ly * lx * m);
    const int cb = b * C_TOT * H_ * W_;
    sIdx[t] = make_int4(cb + y0 * W_ + x0, cb + y0 * W_ + x1,
                        cb + y1 * W_ + x0, cb + y1 * W_ + x1);
  }

  const float indf = th * 1.27323954473516268615f;
  const float i0f  = floorf(indf);
  const float lv   = indf - i0f;
  const float rv   = 1.0f - lv;
  const int ind0 = ((int)i0f) & 7;
  const int o    = t & 7;
  const int ir   = (o - ind0) & 7;
  const int irp  = (ir + 1) & 7;
  const int grp  = t & 56;
  const int chanOff = t * (H_ * W_);

  __syncthreads();

  for (int bin = 0; bin < NBIN; ++bin) {
    float acc = 0.0f;
#pragma unroll
    for (int s = 0; s < 4; ++s) {
      const int4   id = sIdx[bin * 4 + s];
      const float4 w  = sW[bin * 4 + s];
      acc = fmaf(w.x, ft[id.x + chanOff], acc);
      acc = fmaf(w.y, ft[id.y + chanOff], acc);
      acc = fmaf(w.z, ft[id.z + chanOff], acc);
      acc = fmaf(w.w, ft[id.w + chanOff], acc);
    }
    const float v1 = __shfl(acc, grp | ir,  64);
    const float v2 = __shfl(acc, grp | irp, 64);
    outBuf[t * NBIN + bin] = rv * v1 + lv * v2;
  }

  __syncthreads();
  const float4* ob4 = (const float4*)outBuf;
  float4* o4 = (float4*)(out + (size_t)k * PCH);
#pragma unroll 4
  for (int j = t; j < PCH / 4; j += 256) o4[j] = ob4[j];
}

// ---------------------------------------------------------------------------
extern "C" void kernel_launch(void* const* d_in, const int* in_sizes, int n_in,
                              void* d_out, int out_size, void* d_ws, size_t ws_size,
                              hipStream_t stream) {
  const float* features = (const float*)d_in[0];
  const float* rois     = (const float*)d_in[1];
  float* out            = (float*)d_out;
  const int K = in_sizes[1] / 6;

  const size_t ftBytes = (size_t)N_ * C_TOT * H_ * W_ * sizeof(ushort);
  if (ws_size >= ftBytes) {
    ushort* ftT = (ushort*)d_ws;
    dim3 tb(64, 4);
    dim3 tg(W_ / 64, C_TOT / 64, N_ * H_);
    transpose_nchw_nhwc_f16<<<tg, tb, 0, stream>>>(features, ftT);
    os2_rroialign_v7<<<K, 512, 0, stream>>>((const uint4*)ftT, rois, out);
  } else {
    os2_rroialign_nchw<<<K, 256, 0, stream>>>(features, rois, out);
  }
}